// Round 3
// baseline (1420.092 us; speedup 1.0000x reference)
//
#include <hip/hip_runtime.h>

// PLELayer: B=131072, NF=9, E=8 (D0=72), H=64, O=8, T=SE=SH=3.
// Round-3: ALL tensors are fp32 (round-1 NaN = fp32 misread as bf16;
// round-2 absmax == stub absmax = correct math stored as u16 into a fp32
// output buffer, leaving the second half zero). Output: float, [T,B,1].
// Structure: params packed fp32 into d_ws (single base -> s_load with
// literal offsets); fully fused per-element kernel; x[72] fp32 in LDS
// (own column, stride NT, no barriers); hidden-64 in 2 chunks of 32 regs
// with fp32 LDS round-trip so layer-2 k-loop stays rolled (no dynamic
// VGPR indexing -> no scratch spills).

#define NT 128

// ---- parameter layout in ws (fp32), element offsets ----
#define OFF_spec0_W1 0
#define OFF_spec0_b1 41472
#define OFF_spec0_W2 42048
#define OFF_spec0_b2 46656
#define OFF_shar0_W1 46728
#define OFF_shar0_b1 60552
#define OFF_shar0_W2 60744
#define OFF_shar0_b2 62280
#define OFF_gate0_W1 62304
#define OFF_gate0_b1 76128
#define OFF_gate0_W2 76320
#define OFF_gate0_b2 77856
#define OFF_gate0_W3 77880
#define OFF_sgate0_W1 78024
#define OFF_sgate0_b1 82632
#define OFF_sgate0_W2 82696
#define OFF_sgate0_b2 83208
#define OFF_sgate0_W3 83216
#define OFF_spec1_W1 83312
#define OFF_spec1_b1 87920
#define OFF_spec1_W2 88496
#define OFF_spec1_b2 93104
#define OFF_shar1_W1 93176
#define OFF_shar1_b1 94712
#define OFF_shar1_W2 94904
#define OFF_shar1_b2 96440
#define OFF_gate1_W1 96464
#define OFF_gate1_b1 98000
#define OFF_gate1_W2 98192
#define OFF_gate1_b2 99728
#define OFF_gate1_W3 99752
#define OFF_tower_W 99896
#define OFF_tower_b 99920
#define NPARAM 33
#define TOTALP 99923

__device__ const int c_end[NPARAM] = {
  41472,42048,46656,46728,60552,60744,62280,62304,76128,76320,77856,77880,
  78024,82632,82696,83208,83216,83312,87920,88496,93104,93176,94712,94904,
  96440,96464,98000,98192,99728,99752,99896,99920,99923};

struct PSrc { const float* p[NPARAM]; };

__global__ void cvt_kernel(PSrc S, float* __restrict__ dst){
  int i = blockIdx.x*256 + threadIdx.x;
  if (i >= TOTALP) return;
  int a = 0, base = 0;
  #pragma unroll 1
  for (; a < NPARAM-1; a++){
    if (i < c_end[a]) break;
    base = c_end[a];
  }
  dst[i] = S.p[a][i - base];
}

// 72 -> 64(relu, 2 chunks of 32 regs) -> 8(relu).
// xcol/hcol: fp32 LDS columns, stride NT.
__device__ __forceinline__ void unit72(const float* __restrict__ xcol,
    const float* __restrict__ W1, const float* __restrict__ b1,
    const float* __restrict__ W2, const float* __restrict__ b2,
    float* __restrict__ hcol, float o[8])
{
  #pragma unroll
  for (int j=0;j<8;j++) o[j] = b2[j];
  #pragma unroll 1
  for (int c=0;c<2;c++){
    float h[32];
    const float* b1c = b1 + c*32;
    #pragma unroll
    for (int u=0;u<32;u++) h[u] = b1c[u];
    const float* w1c = W1 + c*32;
    #pragma unroll 2
    for (int i=0;i<72;i++){
      float xv = xcol[i*NT];
      const float* wr = w1c + i*64;
      #pragma unroll
      for (int u=0;u<32;u++) h[u] = fmaf(xv, wr[u], h[u]);
    }
    #pragma unroll
    for (int u=0;u<32;u++) hcol[u*NT] = fmaxf(h[u], 0.f);
    const float* w2c = W2 + c*32*8;
    #pragma unroll 2
    for (int k=0;k<32;k++){
      float hv = hcol[k*NT];
      const float* wr = w2c + k*8;
      #pragma unroll
      for (int j=0;j<8;j++) o[j] = fmaf(hv, wr[j], o[j]);
    }
  }
  #pragma unroll
  for (int j=0;j<8;j++) o[j] = fmaxf(o[j], 0.f);
}

// 8 -> 64(relu) -> 8(relu); input fp32 LDS column.
__device__ __forceinline__ void unitL(const float* __restrict__ icol,
    const float* __restrict__ W1, const float* __restrict__ b1,
    const float* __restrict__ W2, const float* __restrict__ b2,
    float* __restrict__ hcol, float o[8])
{
  #pragma unroll
  for (int j=0;j<8;j++) o[j] = b2[j];
  #pragma unroll 1
  for (int c=0;c<2;c++){
    float h[32];
    const float* b1c = b1 + c*32;
    #pragma unroll
    for (int u=0;u<32;u++) h[u] = b1c[u];
    const float* w1c = W1 + c*32;
    #pragma unroll 2
    for (int i=0;i<8;i++){
      float xv = icol[i*NT];
      const float* wr = w1c + i*64;
      #pragma unroll
      for (int u=0;u<32;u++) h[u] = fmaf(xv, wr[u], h[u]);
    }
    #pragma unroll
    for (int u=0;u<32;u++) hcol[u*NT] = fmaxf(h[u], 0.f);
    const float* w2c = W2 + c*32*8;
    #pragma unroll 2
    for (int k=0;k<32;k++){
      float hv = hcol[k*NT];
      const float* wr = w2c + k*8;
      #pragma unroll
      for (int j=0;j<8;j++) o[j] = fmaf(hv, wr[j], o[j]);
    }
  }
  #pragma unroll
  for (int j=0;j<8;j++) o[j] = fmaxf(o[j], 0.f);
}

template<int N>
__device__ __forceinline__ void softmaxT(float (&v)[N]){
  float m = v[0];
  #pragma unroll
  for (int i=1;i<N;i++) m = fmaxf(m, v[i]);
  float s = 0.f;
  #pragma unroll
  for (int i=0;i<N;i++){ v[i] = __expf(v[i]-m); s += v[i]; }
  float inv = 1.f/s;
  #pragma unroll
  for (int i=0;i<N;i++) v[i] *= inv;
}

__global__ __launch_bounds__(NT, 2) void ple_kernel(
    const float* __restrict__ emb, const int* __restrict__ cat,
    const float* __restrict__ P, float* __restrict__ out, int Btot)
{
  __shared__ __align__(16) float xs[72*NT];  // x columns; rows 0..31 reused for level-1 inputs
  __shared__ __align__(16) float hb[32*NT];  // hidden-chunk scratch
  const int tid = threadIdx.x;
  const int b = blockIdx.x*NT + tid;
  float* xcol = xs + tid;
  float* hcol = hb + tid;

  // ---- gather embeddings: x[72] -> LDS fp32 (own column, no barriers) ----
  {
    const int* ci = cat + b*9;
    #pragma unroll
    for (int f=0; f<9; f++){
      int idx = ci[f];
      float4 a  = *(const float4*)(emb + idx*8);
      float4 c2 = *(const float4*)(emb + idx*8 + 4);
      int base = f*8;
      xcol[(base  )*NT] = a.x;  xcol[(base+1)*NT] = a.y;
      xcol[(base+2)*NT] = a.z;  xcol[(base+3)*NT] = a.w;
      xcol[(base+4)*NT] = c2.x; xcol[(base+5)*NT] = c2.y;
      xcol[(base+6)*NT] = c2.z; xcol[(base+7)*NT] = c2.w;
    }
  }

  // ---- level 0: task gates (t unrolled: compile-time w6 indexing) ----
  float w6[3][6];
  #pragma unroll
  for (int t=0;t<3;t++){
    float g8[8];
    unit72(xcol, P+OFF_gate0_W1 + t*4608, P+OFF_gate0_b1 + t*64,
           P+OFF_gate0_W2 + t*512, P+OFF_gate0_b2 + t*8, hcol, g8);
    float lg[6];
    #pragma unroll
    for (int m=0;m<6;m++){
      float s = 0.f;
      #pragma unroll
      for (int j=0;j<8;j++) s = fmaf(g8[j], P[OFF_gate0_W3 + t*48 + j*6 + m], s);
      lg[m] = s;
    }
    softmaxT<6>(lg);
    #pragma unroll
    for (int m=0;m<6;m++) w6[t][m] = lg[m];
  }
  // ---- level 0: shared gate ----
  float w12[12];
  {
    float g8[8];
    unit72(xcol, P+OFF_sgate0_W1, P+OFF_sgate0_b1,
           P+OFF_sgate0_W2, P+OFF_sgate0_b2, hcol, g8);
    #pragma unroll
    for (int m=0;m<12;m++){
      float s = 0.f;
      #pragma unroll
      for (int j=0;j<8;j++) s = fmaf(g8[j], P[OFF_sgate0_W3 + j*12 + m], s);
      w12[m] = s;
    }
    softmaxT<12>(w12);
  }

  // ---- level 0: 12 experts, rolled; gate weights picked by cndmask ----
  float tacc[3][8] = {{0}};
  float sacc[8] = {0};
  #pragma unroll 1
  for (int u=0;u<12;u++){
    const float* W1 = (u<9) ? P+OFF_spec0_W1 + u*4608 : P+OFF_shar0_W1 + (u-9)*4608;
    const float* B1 = (u<9) ? P+OFF_spec0_b1 + u*64   : P+OFF_shar0_b1 + (u-9)*64;
    const float* W2 = (u<9) ? P+OFF_spec0_W2 + u*512  : P+OFF_shar0_W2 + (u-9)*512;
    const float* B2 = (u<9) ? P+OFF_spec0_b2 + u*8    : P+OFF_shar0_b2 + (u-9)*8;
    float o8[8];
    unit72(xcol, W1, B1, W2, B2, hcol, o8);
    #pragma unroll
    for (int t=0;t<3;t++){
      float wsel = 0.f;
      #pragma unroll
      for (int e=0;e<3;e++) if (u == t*3+e) wsel = w6[t][e];
      #pragma unroll
      for (int s=0;s<3;s++) if (u == 9+s)   wsel = w6[t][3+s];
      #pragma unroll
      for (int j=0;j<8;j++) tacc[t][j] = fmaf(wsel, o8[j], tacc[t][j]);
    }
    float ssel = 0.f;
    #pragma unroll
    for (int k=0;k<12;k++) if (u == k) ssel = w12[k];
    #pragma unroll
    for (int j=0;j<8;j++) sacc[j] = fmaf(ssel, o8[j], sacc[j]);
  }

  // ---- level-1 inputs into xs rows 0..31 (x no longer needed) ----
  #pragma unroll
  for (int t=0;t<3;t++)
    #pragma unroll
    for (int j=0;j<8;j++) xcol[(t*8+j)*NT] = tacc[t][j];
  #pragma unroll
  for (int j=0;j<8;j++) xcol[(24+j)*NT] = sacc[j];

  // ---- level 1: task gates (unrolled t) ----
  float w6b[3][6];
  #pragma unroll
  for (int t=0;t<3;t++){
    float g8[8];
    unitL(xcol + t*8*NT, P+OFF_gate1_W1 + t*512, P+OFF_gate1_b1 + t*64,
          P+OFF_gate1_W2 + t*512, P+OFF_gate1_b2 + t*8, hcol, g8);
    float lg[6];
    #pragma unroll
    for (int m=0;m<6;m++){
      float s = 0.f;
      #pragma unroll
      for (int j=0;j<8;j++) s = fmaf(g8[j], P[OFF_gate1_W3 + t*48 + j*6 + m], s);
      lg[m] = s;
    }
    softmaxT<6>(lg);
    #pragma unroll
    for (int m=0;m<6;m++) w6b[t][m] = lg[m];
  }

  // ---- level 1: 12 experts, rolled ----
  float t1[3][8] = {{0}};
  #pragma unroll 1
  for (int u=0;u<12;u++){
    const float* W1 = (u<9) ? P+OFF_spec1_W1 + u*512 : P+OFF_shar1_W1 + (u-9)*512;
    const float* B1 = (u<9) ? P+OFF_spec1_b1 + u*64  : P+OFF_shar1_b1 + (u-9)*64;
    const float* W2 = (u<9) ? P+OFF_spec1_W2 + u*512 : P+OFF_shar1_W2 + (u-9)*512;
    const float* B2 = (u<9) ? P+OFF_spec1_b2 + u*8   : P+OFF_shar1_b2 + (u-9)*8;
    const float* icol = (u<9) ? xcol + (u/3)*8*NT : xcol + 24*NT;
    float o8[8];
    unitL(icol, W1, B1, W2, B2, hcol, o8);
    #pragma unroll
    for (int t=0;t<3;t++){
      float wsel = 0.f;
      #pragma unroll
      for (int e=0;e<3;e++) if (u == t*3+e) wsel = w6b[t][e];
      #pragma unroll
      for (int s=0;s<3;s++) if (u == 9+s)   wsel = w6b[t][3+s];
      #pragma unroll
      for (int j=0;j<8;j++) t1[t][j] = fmaf(wsel, o8[j], t1[t][j]);
    }
  }

  // ---- towers: sigmoid(dot)+store, out[t*B+b] (fp32!) ----
  #pragma unroll
  for (int t=0;t<3;t++){
    float s = P[OFF_tower_b + t];
    #pragma unroll
    for (int j=0;j<8;j++) s = fmaf(t1[t][j], P[OFF_tower_W + t*8 + j], s);
    out[t*Btot + b] = 1.f/(1.f + __expf(-s));
  }
}

extern "C" void kernel_launch(void* const* d_in, const int* in_sizes, int n_in,
                              void* d_out, int out_size, void* d_ws, size_t ws_size,
                              hipStream_t stream)
{
  const float* emb = (const float*)d_in[0];
  const int* cat = (const int*)d_in[34];
  float* out = (float*)d_out;
  float* P = (float*)d_ws;                 // TOTALP fp32 (~400 KB)
  PSrc S;
  for (int k=0;k<NPARAM;k++) S.p[k] = (const float*)d_in[k+1];
  const int B = in_sizes[34] / 9;          // 131072

  cvt_kernel<<<(TOTALP+255)/256, 256, 0, stream>>>(S, P);
  ple_kernel<<<B/NT, NT, 0, stream>>>(emb, cat, P, out, B);
}

// Round 4
// 500.051 us; speedup vs baseline: 2.8399x; 2.8399x over previous
//
#include <hip/hip_runtime.h>

// PLELayer round-4: work-split decomposition.
// Round-3 post-mortem: VALUBusy 16%, occupancy 13% — latency-bound because
// 1 elem/thread gives only 2048 waves (2/SIMD max). This round: 4 threads
// cooperate per element (slot = tid>>6 = wave id in block), 16 level-0 units
// and 15 level-1 units split 4/4/4/4 and 4/4/4/3 across slots -> 8192 waves.
// x + inter-phase tensors packed bf16 in LDS (25,600 B/block -> 6 blocks/CU
// = 24 waves/CU). Layer-2 of each MLP fused in registers (unrolled). Params
// repacked unit-major in d_ws; unit ids wave-uniform via readfirstlane so
// weights ride the scalar path (s_load).

#define NT 256
#define EPB 64

typedef unsigned short u16;
typedef unsigned int u32;

__device__ __forceinline__ float bflo(u32 w){ return __uint_as_float(w << 16); }
__device__ __forceinline__ float bfhi(u32 w){ return __uint_as_float(w & 0xffff0000u); }
__device__ __forceinline__ u32 f2bf(float f){
  u32 v = __float_as_uint(f);
  return (v + 0x7fffu + ((v>>16)&1u)) >> 16;
}
__device__ __forceinline__ u32 pack2(float a, float b){
  return f2bf(a) | (f2bf(b) << 16);
}

// ---- ws layout (fp32), unit-major packed ----
// L0 units 0..8 = spec0 (t*3+e), 9..11 = shar0, 12..14 = gate0, 15 = sgate0
// L1 units 0..8 = spec1, 9..11 = shar1, 12..14 = gate1
#define OFF_L0_W1 0        // [16][72][64]
#define OFF_L0_b1 73728    // [16][64]
#define OFF_L0_W2 74752    // [16][64][8]
#define OFF_L0_b2 82944    // [16][8]
#define OFF_G0_W3 83072    // [3][8][6]
#define OFF_SG0_W3 83216   // [8][12]
#define OFF_L1_W1 83312    // [15][8][64]
#define OFF_L1_b1 90992    // [15][64]
#define OFF_L1_W2 91952    // [15][64][8]
#define OFF_L1_b2 99632    // [15][8]
#define OFF_G1_W3 99752    // [3][8][6]
#define OFF_TW 99896       // [3][8]
#define OFF_Tb 99920       // [3]
#define NPARAM 33
#define TOTALP 99923

// cumulative dst ends, in repack order
__device__ const int c_end[NPARAM] = {
  41472,55296,69120,73728,          // spec0_W1, shar0_W1, gate0_W1, sgate0_W1
  74304,74496,74688,74752,          // spec0_b1, shar0_b1, gate0_b1, sgate0_b1
  79360,80896,82432,82944,          // spec0_W2, shar0_W2, gate0_W2, sgate0_W2
  83016,83040,83064,83072,          // spec0_b2, shar0_b2, gate0_b2, sgate0_b2
  83216,83312,                      // gate0_W3, sgate0_W3
  87920,89456,90992,                // spec1_W1, shar1_W1, gate1_W1
  91568,91760,91952,                // spec1_b1, shar1_b1, gate1_b1
  96560,98096,99632,                // spec1_W2, shar1_W2, gate1_W2
  99704,99728,99752,                // spec1_b2, shar1_b2, gate1_b2
  99896,99920,99923};               // gate1_W3, tower_W, tower_b

struct PSrc { const float* p[NPARAM]; };

__global__ void cvt_kernel(PSrc S, float* __restrict__ dst){
  int i = blockIdx.x*256 + threadIdx.x;
  if (i >= TOTALP) return;
  int a = 0, base = 0;
  #pragma unroll 1
  for (; a < NPARAM-1; a++){
    if (i < c_end[a]) break;
    base = c_end[a];
  }
  dst[i] = S.p[a][i - base];
}

template<int N>
__device__ __forceinline__ void softmaxT(float (&v)[N]){
  float m = v[0];
  #pragma unroll
  for (int i=1;i<N;i++) m = fmaxf(m, v[i]);
  float s = 0.f;
  #pragma unroll
  for (int i=0;i<N;i++){ v[i] = __expf(v[i]-m); s += v[i]; }
  float inv = 1.f/s;
  #pragma unroll
  for (int i=0;i<N;i++) v[i] *= inv;
}

__global__ __launch_bounds__(NT, 6) void ple_kernel(
    const float* __restrict__ emb, const int* __restrict__ cat,
    const float* __restrict__ P, float* __restrict__ out, int Btot)
{
  __shared__ u32 xs[36*EPB];  // packed bf16 x pairs; rows 0..15 reused for level-1 inputs
  __shared__ u32 ob[64*EPB];  // 16 units x 4 words x 64 elem (bf16 pairs)
  const int tid = threadIdx.x;
  const int e = tid & 63;
  const int su = __builtin_amdgcn_readfirstlane(tid >> 6);  // slot == wave id
  const int eg = blockIdx.x*EPB + e;

  // ---- phase 0: gather x[72] -> bf16 pairs in LDS (fields split by slot) ----
  {
    auto ldf = [&](int f){
      int idx = cat[eg*9 + f];
      const float* ep = emb + (long)idx*8;
      float4 a = *(const float4*)ep;
      float4 b = *(const float4*)(ep+4);
      int r = f*4;
      xs[(r+0)*EPB + e] = pack2(a.x, a.y);
      xs[(r+1)*EPB + e] = pack2(a.z, a.w);
      xs[(r+2)*EPB + e] = pack2(b.x, b.y);
      xs[(r+3)*EPB + e] = pack2(b.z, b.w);
    };
    ldf(su); ldf(su+4);
    if (su == 0) ldf(8);
  }
  __syncthreads();

  // ---- phase 1: 16 level-0 units (72->64 relu ->8 relu), 4 per slot ----
  #pragma unroll 1
  for (int k=0;k<4;k++){
    const int u = su*4 + k;                       // wave-uniform
    const float* W1 = P + OFF_L0_W1 + u*4608;
    const float* b1 = P + OFF_L0_b1 + u*64;
    const float* W2 = P + OFF_L0_W2 + u*512;
    const float* b2 = P + OFF_L0_b2 + u*8;
    float acc[8];
    #pragma unroll
    for (int j=0;j<8;j++) acc[j] = b2[j];
    #pragma unroll 1
    for (int c=0;c<2;c++){
      float h[32];
      #pragma unroll
      for (int q=0;q<32;q++) h[q] = b1[c*32+q];
      const float* w1c = W1 + c*32;
      #pragma unroll 2
      for (int ip=0; ip<36; ip++){
        u32 w = xs[ip*EPB + e];
        float x0 = bflo(w), x1 = bfhi(w);
        const float* r0 = w1c + (2*ip)*64;
        const float* r1 = r0 + 64;
        #pragma unroll
        for (int q=0;q<32;q++) h[q] = fmaf(x0, r0[q], h[q]);
        #pragma unroll
        for (int q=0;q<32;q++) h[q] = fmaf(x1, r1[q], h[q]);
      }
      const float* w2c = W2 + (c*32)*8;
      #pragma unroll
      for (int q=0;q<32;q++){
        float hv = fmaxf(h[q], 0.f);
        #pragma unroll
        for (int j=0;j<8;j++) acc[j] = fmaf(hv, w2c[q*8+j], acc[j]);
      }
    }
    #pragma unroll
    for (int jw=0;jw<4;jw++)
      ob[(u*4+jw)*EPB + e] = pack2(fmaxf(acc[2*jw],0.f), fmaxf(acc[2*jw+1],0.f));
  }
  __syncthreads();

  // ---- phase 2: level-0 gates softmax + mixing -> level-1 inputs (xs rows 0..15) ----
  if (su < 3){
    const int t = su;
    float g8[8];
    #pragma unroll
    for (int jw=0;jw<4;jw++){
      u32 w = ob[((12+t)*4+jw)*EPB + e];
      g8[2*jw] = bflo(w); g8[2*jw+1] = bfhi(w);
    }
    float lg[6];
    #pragma unroll
    for (int m=0;m<6;m++){
      float s = 0.f;
      #pragma unroll
      for (int j=0;j<8;j++) s = fmaf(g8[j], P[OFF_G0_W3 + t*48 + j*6 + m], s);
      lg[m] = s;
    }
    softmaxT<6>(lg);
    float in8[8] = {0,0,0,0,0,0,0,0};
    #pragma unroll
    for (int x=0;x<6;x++){
      const int uu = (x<3) ? t*3+x : 9+(x-3);
      float wv = lg[x];
      #pragma unroll
      for (int jw=0;jw<4;jw++){
        u32 w = ob[(uu*4+jw)*EPB + e];
        in8[2*jw]   = fmaf(wv, bflo(w), in8[2*jw]);
        in8[2*jw+1] = fmaf(wv, bfhi(w), in8[2*jw+1]);
      }
    }
    #pragma unroll
    for (int jw=0;jw<4;jw++)
      xs[(t*4+jw)*EPB + e] = pack2(in8[2*jw], in8[2*jw+1]);
  } else {
    float g8[8];
    #pragma unroll
    for (int jw=0;jw<4;jw++){
      u32 w = ob[(15*4+jw)*EPB + e];
      g8[2*jw] = bflo(w); g8[2*jw+1] = bfhi(w);
    }
    float lw[12];
    #pragma unroll
    for (int m=0;m<12;m++){
      float s = 0.f;
      #pragma unroll
      for (int j=0;j<8;j++) s = fmaf(g8[j], P[OFF_SG0_W3 + j*12 + m], s);
      lw[m] = s;
    }
    softmaxT<12>(lw);
    float in8[8] = {0,0,0,0,0,0,0,0};
    #pragma unroll
    for (int uu=0;uu<12;uu++){
      float wv = lw[uu];
      #pragma unroll
      for (int jw=0;jw<4;jw++){
        u32 w = ob[(uu*4+jw)*EPB + e];
        in8[2*jw]   = fmaf(wv, bflo(w), in8[2*jw]);
        in8[2*jw+1] = fmaf(wv, bfhi(w), in8[2*jw+1]);
      }
    }
    #pragma unroll
    for (int jw=0;jw<4;jw++)
      xs[(12+jw)*EPB + e] = pack2(in8[2*jw], in8[2*jw+1]);
  }
  __syncthreads();

  // ---- phase 3: 15 level-1 units (8->64 relu ->8 relu), 4/4/4/3 per slot ----
  #pragma unroll 1
  for (int k=0;k<4;k++){
    const int u = su*4 + k;                       // wave-uniform
    if (u >= 15) break;
    const int r0 = (u<9) ? (u/3)*4 : ((u<12) ? 12 : (u-12)*4);
    float in8[8];
    #pragma unroll
    for (int jw=0;jw<4;jw++){
      u32 w = xs[(r0+jw)*EPB + e];
      in8[2*jw] = bflo(w); in8[2*jw+1] = bfhi(w);
    }
    const float* W1 = P + OFF_L1_W1 + u*512;
    const float* b1 = P + OFF_L1_b1 + u*64;
    const float* W2 = P + OFF_L1_W2 + u*512;
    const float* b2 = P + OFF_L1_b2 + u*8;
    float acc[8];
    #pragma unroll
    for (int j=0;j<8;j++) acc[j] = b2[j];
    #pragma unroll 1
    for (int c=0;c<2;c++){
      float h[32];
      #pragma unroll
      for (int q=0;q<32;q++) h[q] = b1[c*32+q];
      #pragma unroll
      for (int i=0;i<8;i++){
        const float* r = W1 + i*64 + c*32;
        #pragma unroll
        for (int q=0;q<32;q++) h[q] = fmaf(in8[i], r[q], h[q]);
      }
      const float* w2c = W2 + (c*32)*8;
      #pragma unroll
      for (int q=0;q<32;q++){
        float hv = fmaxf(h[q], 0.f);
        #pragma unroll
        for (int j=0;j<8;j++) acc[j] = fmaf(hv, w2c[q*8+j], acc[j]);
      }
    }
    #pragma unroll
    for (int jw=0;jw<4;jw++)
      ob[(u*4+jw)*EPB + e] = pack2(fmaxf(acc[2*jw],0.f), fmaxf(acc[2*jw+1],0.f));
  }
  __syncthreads();

  // ---- phase 4: level-1 gates + mixing + towers (slots 0..2 = tasks) ----
  if (su < 3){
    const int t = su;
    float g8[8];
    #pragma unroll
    for (int jw=0;jw<4;jw++){
      u32 w = ob[((12+t)*4+jw)*EPB + e];
      g8[2*jw] = bflo(w); g8[2*jw+1] = bfhi(w);
    }
    float lg[6];
    #pragma unroll
    for (int m=0;m<6;m++){
      float s = 0.f;
      #pragma unroll
      for (int j=0;j<8;j++) s = fmaf(g8[j], P[OFF_G1_W3 + t*48 + j*6 + m], s);
      lg[m] = s;
    }
    softmaxT<6>(lg);
    float t1[8] = {0,0,0,0,0,0,0,0};
    #pragma unroll
    for (int x=0;x<6;x++){
      const int uu = (x<3) ? t*3+x : 9+(x-3);
      float wv = lg[x];
      #pragma unroll
      for (int jw=0;jw<4;jw++){
        u32 w = ob[(uu*4+jw)*EPB + e];
        t1[2*jw]   = fmaf(wv, bflo(w), t1[2*jw]);
        t1[2*jw+1] = fmaf(wv, bfhi(w), t1[2*jw+1]);
      }
    }
    float s = P[OFF_Tb + t];
    #pragma unroll
    for (int j=0;j<8;j++) s = fmaf(t1[j], P[OFF_TW + t*8 + j], s);
    out[t*Btot + blockIdx.x*EPB + e] = 1.f/(1.f + __expf(-s));
  }
}

extern "C" void kernel_launch(void* const* d_in, const int* in_sizes, int n_in,
                              void* d_out, int out_size, void* d_ws, size_t ws_size,
                              hipStream_t stream)
{
  const float* emb = (const float*)d_in[0];
  const int* cat = (const int*)d_in[34];
  float* out = (float*)d_out;
  float* P = (float*)d_ws;
  // source pointers in repack order (see c_end)
  const int order[NPARAM] = {1,5,9,14, 2,6,10,15, 3,7,11,16, 4,8,12,17,
                             13,18, 19,23,27, 20,24,28, 21,25,29, 22,26,30,
                             31,32,33};
  PSrc S;
  for (int k=0;k<NPARAM;k++) S.p[k] = (const float*)d_in[order[k]];
  const int B = in_sizes[34] / 9;   // 131072

  cvt_kernel<<<(TOTALP+255)/256, 256, 0, stream>>>(S, P);
  ple_kernel<<<B/EPB, NT, 0, stream>>>(emb, cat, P, out, B);
}

// Round 5
// 233.039 us; speedup vs baseline: 6.0938x; 2.1458x over previous
//
#include <hip/hip_runtime.h>

// PLELayer round-5: MFMA for level-0 (75% of FLOP), VALU for the rest.
// Round-4 post-mortem: VALUBusy 60%, fp32-VALU floor 163us. Level-0's 16
// units of 72->64->8 move to bf16 MFMA 16x16x32 (dense peak ~2.5PF).
// Per block: 64 elems, 4 waves; wave w owns units 4w..4w+3 and runs all
// 4 M-tiles (16 elems each). W1/W2 pre-swizzled to B-frag order in d_ws by
// cvt_kernel; x gathered to LDS bf16 [e][96] (zero-padded K) readable as
// A-frags via ds_read_b128; H relu'd to bf16 in per-wave LDS then re-read
// as A-frags for the W2 GEMM (N padded 8->16, zero cols). Level-1 + gates
// keep round-4's proven VALU structure (4 thr/elem, slot = wave).

#define NT 256
#define EPB 64

typedef unsigned short u16;
typedef unsigned int u32;
typedef __attribute__((ext_vector_type(8))) short short8;   // 8 bf16
typedef __attribute__((ext_vector_type(4))) float floatx4;

__device__ __forceinline__ float bflo(u32 w){ return __uint_as_float(w << 16); }
__device__ __forceinline__ float bfhi(u32 w){ return __uint_as_float(w & 0xffff0000u); }
__device__ __forceinline__ u32 f2bf(float f){
  u32 v = __float_as_uint(f);
  return (v + 0x7fffu + ((v>>16)&1u)) >> 16;
}
__device__ __forceinline__ u32 pack2(float a, float b){
  return f2bf(a) | (f2bf(b) << 16);
}

// ---- ws layout ----
// u32 region: W1F frags [16u][3s][4t][64lane][4 u32]  = 49152 u32
//             W2F frags [16u][2ks][64lane][4 u32]     =  8192 u32
// fp32 region (index == float index from base):
#define W2F_U32  49152
#define OFF_b1P  57344   // [16][64]
#define OFF_b2P  58368   // [16][16] (cols 8..15 zero)
#define OFF_G0W3 58624   // [3][8][6]
#define OFF_SG0W3 58768  // [8][12]
#define OFF_L1W1 58864   // [15][8][64]
#define OFF_L1b1 66544   // [15][64]
#define OFF_L1W2 67504   // [15][64][8]
#define OFF_L1b2 75184   // [15][8]
#define OFF_G1W3 75304   // [3][8][6]
#define OFF_TW   75448   // [3][8]
#define OFF_Tb   75472   // [3]
#define CVT_TOTAL 75475

struct PSrc { const float* p[33]; };
// p[k] = d_in[k+1]: 0 spec0_W1, 1 spec0_b1, 2 spec0_W2, 3 spec0_b2,
// 4..7 shar0, 8..12 gate0(+W3), 13..17 sgate0(+W3), 18..21 spec1,
// 22..25 shar1, 26..30 gate1(+W3), 31 tower_W, 32 tower_b

__global__ void cvt_kernel(PSrc S, u32* __restrict__ wsU, float* __restrict__ wsF){
  int i = blockIdx.x*256 + threadIdx.x;
  if (i >= CVT_TOTAL) return;
  if (i < 49152){  // W1F: lane gets W1[k=s*32+q*8+j][h=t*16+(l&15)], k>=72 -> 0
    int j2 = i & 3, l = (i>>2)&63, tt = (i>>8)&3;
    int rest = i >> 10; int s = rest % 3, u = rest / 3;
    int k0 = s*32 + (l>>4)*8 + 2*j2;
    int h  = tt*16 + (l&15);
    const float* src = (u<9)  ? S.p[0]  + (u*72)*64
                     : (u<12) ? S.p[4]  + ((u-9)*72)*64
                     : (u<15) ? S.p[8]  + ((u-12)*72)*64
                              : S.p[13];
    float lo = (k0   < 72) ? src[(k0  )*64 + h] : 0.f;
    float hi = (k0+1 < 72) ? src[(k0+1)*64 + h] : 0.f;
    wsU[i] = pack2(lo, hi);
    return;
  }
  i -= 49152;
  if (i < 8192){   // W2F: lane gets W2[k=ks*32+q*8+j][n=l&15], n>=8 -> 0
    int j2 = i & 3, l = (i>>2)&63, ks = (i>>8)&1, u = i>>9;
    int k0 = ks*32 + (l>>4)*8 + 2*j2;
    int n = l & 15;
    const float* src = (u<9)  ? S.p[2]  + u*512
                     : (u<12) ? S.p[6]  + (u-9)*512
                     : (u<15) ? S.p[10] + (u-12)*512
                              : S.p[15];
    float lo = (n<8) ? src[(k0  )*8 + n] : 0.f;
    float hi = (n<8) ? src[(k0+1)*8 + n] : 0.f;
    wsU[W2F_U32 + i] = pack2(lo, hi);
    return;
  }
  i -= 8192;
  if (i < 1024){   // b1P
    int u = i>>6, h = i&63;
    const float* src = (u<9) ? S.p[1]+u*64 : (u<12) ? S.p[5]+(u-9)*64
                     : (u<15) ? S.p[9]+(u-12)*64 : S.p[14];
    wsF[OFF_b1P + i] = src[h];
    return;
  }
  i -= 1024;
  if (i < 256){    // b2P padded
    int u = i>>4, n = i&15;
    const float* src = (u<9) ? S.p[3]+u*8 : (u<12) ? S.p[7]+(u-9)*8
                     : (u<15) ? S.p[11]+(u-12)*8 : S.p[16];
    wsF[OFF_b2P + i] = (n<8) ? src[n] : 0.f;
    return;
  }
  i -= 256;
  if (i < 144){ wsF[OFF_G0W3 + i] = S.p[12][i]; return; }
  i -= 144;
  if (i < 96){ wsF[OFF_SG0W3 + i] = S.p[17][i]; return; }
  i -= 96;
  if (i < 7680){
    int u = i>>9, r = i&511;
    const float* src = (u<9) ? S.p[18]+u*512 : (u<12) ? S.p[22]+(u-9)*512 : S.p[26]+(u-12)*512;
    wsF[OFF_L1W1 + i] = src[r]; return;
  }
  i -= 7680;
  if (i < 960){
    int u = i>>6, r = i&63;
    const float* src = (u<9) ? S.p[19]+u*64 : (u<12) ? S.p[23]+(u-9)*64 : S.p[27]+(u-12)*64;
    wsF[OFF_L1b1 + i] = src[r]; return;
  }
  i -= 960;
  if (i < 7680){
    int u = i>>9, r = i&511;
    const float* src = (u<9) ? S.p[20]+u*512 : (u<12) ? S.p[24]+(u-9)*512 : S.p[28]+(u-12)*512;
    wsF[OFF_L1W2 + i] = src[r]; return;
  }
  i -= 7680;
  if (i < 120){
    int u = i>>3, r = i&7;
    const float* src = (u<9) ? S.p[21]+u*8 : (u<12) ? S.p[25]+(u-9)*8 : S.p[29]+(u-12)*8;
    wsF[OFF_L1b2 + i] = src[r]; return;
  }
  i -= 120;
  if (i < 144){ wsF[OFF_G1W3 + i] = S.p[30][i]; return; }
  i -= 144;
  if (i < 24){ wsF[OFF_TW + i] = S.p[31][i]; return; }
  i -= 24;
  wsF[OFF_Tb + i] = S.p[32][i];
}

template<int N>
__device__ __forceinline__ void softmaxT(float (&v)[N]){
  float m = v[0];
  #pragma unroll
  for (int i=1;i<N;i++) m = fmaxf(m, v[i]);
  float s = 0.f;
  #pragma unroll
  for (int i=0;i<N;i++){ v[i] = __expf(v[i]-m); s += v[i]; }
  float inv = 1.f/s;
  #pragma unroll
  for (int i=0;i<N;i++) v[i] *= inv;
}

__global__ __launch_bounds__(NT, 4) void ple_kernel(
    const float* __restrict__ emb, const int* __restrict__ cat,
    const u32* __restrict__ wsU, const float* __restrict__ P,
    float* __restrict__ out, int Btot)
{
  // LDS map (u32 units): xsA [64e][48] bf16-pairs (x, k-padded to 96);
  // ob [64 rows][65] (pitch 65 kills the e-stride-64 bank alias);
  // hbW: per-wave [16e][72] bf16 H scratch.
  __shared__ u32 S_[9536];
  u32* xsA = S_;
  u32* ob  = S_ + 3072;
  u32* hbW = S_ + 7232;
  const int tid = threadIdx.x;
  const int e = tid & 63;
  const int su = __builtin_amdgcn_readfirstlane(tid >> 6);
  const int lane = tid & 63;
  const int q = lane >> 4;
  const int c16 = lane & 15;

  // ---- phase 0: gather x -> xsA bf16 [e][96], zero pad k 72..95 ----
  {
    const int eg = blockIdx.x*EPB + e;
    auto ldf = [&](int f){
      int idx = cat[eg*9 + f];
      const float* ep = emb + (long)idx*8;
      float4 a = *(const float4*)ep;
      float4 b = *(const float4*)(ep+4);
      u32* row = xsA + e*48 + f*4;
      row[0] = pack2(a.x, a.y); row[1] = pack2(a.z, a.w);
      row[2] = pack2(b.x, b.y); row[3] = pack2(b.z, b.w);
    };
    ldf(su); ldf(su+4);
    if (su == 0) ldf(8);
    u32* zr = xsA + e*48 + 36 + su*3;
    zr[0] = 0; zr[1] = 0; zr[2] = 0;
  }
  __syncthreads();

  // ---- phase 1: level-0 MFMA. wave su owns units 4su..4su+3 ----
  {
    u16* hb = (u16*)(hbW + su*576);   // [16][72] bf16
    #pragma unroll 1
    for (int k4 = 0; k4 < 4; k4++){
      const int u = su*4 + k4;
      short8 bf[3][4];
      #pragma unroll
      for (int s=0;s<3;s++)
        #pragma unroll
        for (int t=0;t<4;t++)
          bf[s][t] = *(const short8*)(wsU + (((u*3+s)*4+t)*64 + lane)*4);
      float bias[4];
      #pragma unroll
      for (int t=0;t<4;t++) bias[t] = P[OFF_b1P + u*64 + t*16 + c16];
      const float ob2 = P[OFF_b2P + u*16 + c16];
      short8 w2f[2];
      #pragma unroll
      for (int ks=0;ks<2;ks++)
        w2f[ks] = *(const short8*)(wsU + W2F_U32 + ((u*2+ks)*64 + lane)*4);

      #pragma unroll 1
      for (int m=0;m<4;m++){
        short8 af[3];
        #pragma unroll
        for (int s=0;s<3;s++)
          af[s] = *(const short8*)(xsA + (m*16 + c16)*48 + s*16 + q*4);
        floatx4 acc[4];
        #pragma unroll
        for (int t=0;t<4;t++) acc[t] = (floatx4){bias[t],bias[t],bias[t],bias[t]};
        #pragma unroll
        for (int s=0;s<3;s++)
          #pragma unroll
          for (int t=0;t<4;t++)
            acc[t] = __builtin_amdgcn_mfma_f32_16x16x32_bf16(af[s], bf[s][t], acc[t], 0,0,0);
        // H (C-layout: row e_loc=q*4+r, col h=t*16+c16) -> relu -> bf16 LDS
        #pragma unroll
        for (int t=0;t<4;t++)
          #pragma unroll
          for (int r=0;r<4;r++)
            hb[(q*4+r)*72 + t*16 + c16] = (u16)f2bf(fmaxf(acc[t][r], 0.f));
        // stage B: O = relu(H*W2 + b2), A-frag re-read from hb
        floatx4 oc = (floatx4){ob2, ob2, ob2, ob2};
        #pragma unroll
        for (int ks=0;ks<2;ks++){
          short8 haf = *(const short8*)(hb + c16*72 + ks*32 + q*8);
          oc = __builtin_amdgcn_mfma_f32_16x16x32_bf16(haf, w2f[ks], oc, 0,0,0);
        }
        if (c16 < 8){
          u16* obp = (u16*)ob;
          #pragma unroll
          for (int r=0;r<4;r++)
            obp[(u*4 + (c16>>1))*130 + (m*16 + q*4 + r)*2 + (c16&1)] =
                (u16)f2bf(fmaxf(oc[r], 0.f));
        }
      }
    }
  }
  __syncthreads();

  // ---- phase 2: level-0 gates + mixing -> l1in rows (xsA reuse) ----
  u32* l1in = xsA;   // [16 rows][64]
  if (su < 3){
    const int t = su;
    float g8[8];
    #pragma unroll
    for (int jw=0;jw<4;jw++){
      u32 w = ob[((12+t)*4+jw)*65 + e];
      g8[2*jw] = bflo(w); g8[2*jw+1] = bfhi(w);
    }
    float lg[6];
    #pragma unroll
    for (int m=0;m<6;m++){
      float s = 0.f;
      #pragma unroll
      for (int j=0;j<8;j++) s = fmaf(g8[j], P[OFF_G0W3 + t*48 + j*6 + m], s);
      lg[m] = s;
    }
    softmaxT<6>(lg);
    float in8[8] = {0,0,0,0,0,0,0,0};
    #pragma unroll
    for (int x=0;x<6;x++){
      const int uu = (x<3) ? t*3+x : 9+(x-3);
      float wv = lg[x];
      #pragma unroll
      for (int jw=0;jw<4;jw++){
        u32 w = ob[(uu*4+jw)*65 + e];
        in8[2*jw]   = fmaf(wv, bflo(w), in8[2*jw]);
        in8[2*jw+1] = fmaf(wv, bfhi(w), in8[2*jw+1]);
      }
    }
    #pragma unroll
    for (int jw=0;jw<4;jw++)
      l1in[(t*4+jw)*64 + e] = pack2(in8[2*jw], in8[2*jw+1]);
  } else {
    float g8[8];
    #pragma unroll
    for (int jw=0;jw<4;jw++){
      u32 w = ob[(15*4+jw)*65 + e];
      g8[2*jw] = bflo(w); g8[2*jw+1] = bfhi(w);
    }
    float lw[12];
    #pragma unroll
    for (int m=0;m<12;m++){
      float s = 0.f;
      #pragma unroll
      for (int j=0;j<8;j++) s = fmaf(g8[j], P[OFF_SG0W3 + j*12 + m], s);
      lw[m] = s;
    }
    softmaxT<12>(lw);
    float in8[8] = {0,0,0,0,0,0,0,0};
    #pragma unroll
    for (int uu=0;uu<12;uu++){
      float wv = lw[uu];
      #pragma unroll
      for (int jw=0;jw<4;jw++){
        u32 w = ob[(uu*4+jw)*65 + e];
        in8[2*jw]   = fmaf(wv, bflo(w), in8[2*jw]);
        in8[2*jw+1] = fmaf(wv, bfhi(w), in8[2*jw+1]);
      }
    }
    #pragma unroll
    for (int jw=0;jw<4;jw++)
      l1in[(12+jw)*64 + e] = pack2(in8[2*jw], in8[2*jw+1]);
  }
  __syncthreads();

  // ---- phase 3: 15 level-1 units (8->64 relu ->8 relu), VALU ----
  #pragma unroll 1
  for (int k=0;k<4;k++){
    const int u = su*4 + k;
    if (u >= 15) break;
    const int r0 = (u<9) ? (u/3)*4 : ((u<12) ? 12 : (u-12)*4);
    float in8[8];
    #pragma unroll
    for (int jw=0;jw<4;jw++){
      u32 w = l1in[(r0+jw)*64 + e];
      in8[2*jw] = bflo(w); in8[2*jw+1] = bfhi(w);
    }
    const float* W1 = P + OFF_L1W1 + u*512;
    const float* b1 = P + OFF_L1b1 + u*64;
    const float* W2 = P + OFF_L1W2 + u*512;
    const float* b2 = P + OFF_L1b2 + u*8;
    float acc[8];
    #pragma unroll
    for (int j=0;j<8;j++) acc[j] = b2[j];
    #pragma unroll 1
    for (int c=0;c<2;c++){
      float h[32];
      #pragma unroll
      for (int qq=0;qq<32;qq++) h[qq] = b1[c*32+qq];
      #pragma unroll
      for (int i2=0;i2<8;i2++){
        const float* r = W1 + i2*64 + c*32;
        #pragma unroll
        for (int qq=0;qq<32;qq++) h[qq] = fmaf(in8[i2], r[qq], h[qq]);
      }
      const float* w2c = W2 + (c*32)*8;
      #pragma unroll
      for (int qq=0;qq<32;qq++){
        float hv = fmaxf(h[qq], 0.f);
        #pragma unroll
        for (int j=0;j<8;j++) acc[j] = fmaf(hv, w2c[qq*8+j], acc[j]);
      }
    }
    #pragma unroll
    for (int jw=0;jw<4;jw++)
      ob[(u*4+jw)*65 + e] = pack2(fmaxf(acc[2*jw],0.f), fmaxf(acc[2*jw+1],0.f));
  }
  __syncthreads();

  // ---- phase 4: level-1 gates + mixing + towers ----
  if (su < 3){
    const int t = su;
    float g8[8];
    #pragma unroll
    for (int jw=0;jw<4;jw++){
      u32 w = ob[((12+t)*4+jw)*65 + e];
      g8[2*jw] = bflo(w); g8[2*jw+1] = bfhi(w);
    }
    float lg[6];
    #pragma unroll
    for (int m=0;m<6;m++){
      float s = 0.f;
      #pragma unroll
      for (int j=0;j<8;j++) s = fmaf(g8[j], P[OFF_G1W3 + t*48 + j*6 + m], s);
      lg[m] = s;
    }
    softmaxT<6>(lg);
    float t1[8] = {0,0,0,0,0,0,0,0};
    #pragma unroll
    for (int x=0;x<6;x++){
      const int uu = (x<3) ? t*3+x : 9+(x-3);
      float wv = lg[x];
      #pragma unroll
      for (int jw=0;jw<4;jw++){
        u32 w = ob[(uu*4+jw)*65 + e];
        t1[2*jw]   = fmaf(wv, bflo(w), t1[2*jw]);
        t1[2*jw+1] = fmaf(wv, bfhi(w), t1[2*jw+1]);
      }
    }
    float s = P[OFF_Tb + t];
    #pragma unroll
    for (int j=0;j<8;j++) s = fmaf(t1[j], P[OFF_TW + t*8 + j], s);
    out[t*Btot + blockIdx.x*EPB + e] = 1.f/(1.f + __expf(-s));
  }
}

extern "C" void kernel_launch(void* const* d_in, const int* in_sizes, int n_in,
                              void* d_out, int out_size, void* d_ws, size_t ws_size,
                              hipStream_t stream)
{
  const float* emb = (const float*)d_in[0];
  const int* cat = (const int*)d_in[34];
  float* out = (float*)d_out;
  u32* wsU = (u32*)d_ws;
  float* wsF = (float*)d_ws;
  PSrc S;
  for (int k=0;k<33;k++) S.p[k] = (const float*)d_in[k+1];
  const int B = in_sizes[34] / 9;   // 131072

  cvt_kernel<<<(CVT_TOTAL+255)/256, 256, 0, stream>>>(S, wsU, wsF);
  ple_kernel<<<B/EPB, NT, 0, stream>>>(emb, cat, wsU, wsF, out, B);
}

// Round 6
// 193.730 us; speedup vs baseline: 7.3303x; 1.2029x over previous
//
#include <hip/hip_runtime.h>
#include <hip/hip_bf16.h>

// PLELayer round-6: both levels on MFMA.
// Round-5 post-mortem: ple 120us, VALUBusy 67%, MfmaUtil 10% — phase-3
// (level-1 VALU, ~2G fp32 FMA) + bf16 pack overhead dominate VALU issue.
// This round: level-1's 15 units also run 16x16x32 bf16 MFMA (K=8 zero-
// padded to 32: q>=1 lanes of A and B carry zeros). H LDS staging uses a
// k-permutation pi applied jointly to H storage and W2's pre-swizzled
// k-order (sum over k is permutation-invariant) so H packs as u32 pairs
// (halved epilogue) while A-frag ds_read_b128 stays 16B-aligned.
// l1in stored per-element A-frag-readable with a zero region selected by
// one cndmask on the LDS offset. Gates/mixing stay VALU (tiny).

#define NT 256
#define EPB 64

typedef unsigned short u16;
typedef unsigned int u32;
typedef __attribute__((ext_vector_type(8))) short short8;   // 8 bf16
typedef __attribute__((ext_vector_type(4))) float floatx4;

__device__ __forceinline__ float bflo(u32 w){ return __uint_as_float(w << 16); }
__device__ __forceinline__ float bfhi(u32 w){ return __uint_as_float(w & 0xffff0000u); }
__device__ __forceinline__ u32 f2bf(float f){
  u32 v = __float_as_uint(f);
  return (v + 0x7fffu + ((v>>16)&1u)) >> 16;
}
__device__ __forceinline__ u32 pk2(float a, float b){
  __hip_bfloat162 h2 = __float22bfloat162_rn(make_float2(a, b));
  u32 r; __builtin_memcpy(&r, &h2, sizeof(r)); return r;
}

// pi: storage-k s -> real h for the H/W2 pair (both levels).
__device__ __forceinline__ int pi_h(int s){
  return (s&1)*16 + (s>>1) + ((s>=32) ? 16 : 0);
}

// ---- ws layout ----
// u32 frags:
#define W1F0 0          // [16u][3s][4t][64l][4]  = 49152
#define W2F0 49152      // [16u][2ks][64l][4]     =  8192
#define W1F1 57344      // [15u][4t][64l][4]      = 15360
#define W2F1 72704      // [15u][2ks][64l][4]     =  7680
// fp32 (same index space):
#define OFF_b1P0 80384  // [16][64]
#define OFF_b2P0 81408  // [16][16] cols 8..15 zero
#define OFF_b1P1 81664  // [15][64]
#define OFF_b2P1 82624  // [15][16] cols 8..15 zero
#define OFF_G0W3 82864  // [3][8][6]
#define OFF_SG0W3 83008 // [8][12]
#define OFF_G1W3 83104  // [3][8][6]
#define OFF_TW   83248  // [3][8]
#define OFF_Tb   83272  // [3]
#define CVT_TOTAL 83275

struct PSrc { const float* p[33]; };
// p[k]=d_in[k+1]: 0..3 spec0(W1,b1,W2,b2), 4..7 shar0, 8..11 gate0, 12 gate0_W3,
// 13..16 sgate0, 17 sgate0_W3, 18..21 spec1, 22..25 shar1, 26..29 gate1,
// 30 gate1_W3, 31 tower_W, 32 tower_b

__global__ void cvt_kernel(PSrc S, u32* __restrict__ wsU, float* __restrict__ wsF){
  int i = blockIdx.x*256 + threadIdx.x;
  if (i >= CVT_TOTAL) return;
  if (i < 49152){  // W1F0: B[k=s*32+q*8+j][h=t*16+c16], k>=72 -> 0 (identity k)
    int j2 = i & 3, l = (i>>2)&63, tt = (i>>8)&3;
    int rest = i >> 10; int s = rest % 3, u = rest / 3;
    int k0 = s*32 + (l>>4)*8 + 2*j2;
    int h  = tt*16 + (l&15);
    const float* src = (u<9)  ? S.p[0]  + (u*72)*64
                     : (u<12) ? S.p[4]  + ((u-9)*72)*64
                     : (u<15) ? S.p[8]  + ((u-12)*72)*64
                              : S.p[13];
    float lo = (k0   < 72) ? src[(k0  )*64 + h] : 0.f;
    float hi = (k0+1 < 72) ? src[(k0+1)*64 + h] : 0.f;
    wsU[i] = pk2(lo, hi);
    return;
  }
  i -= 49152;
  if (i < 8192){   // W2F0: B[k_storage][n=c16], pi-permuted k, n>=8 -> 0
    int j2 = i & 3, l = (i>>2)&63, ks = (i>>8)&1, u = i>>9;
    int s0 = ks*32 + (l>>4)*8 + 2*j2;
    int n = l & 15;
    const float* src = (u<9)  ? S.p[2]  + u*512
                     : (u<12) ? S.p[6]  + (u-9)*512
                     : (u<15) ? S.p[10] + (u-12)*512
                              : S.p[15];
    float lo = (n<8) ? src[pi_h(s0  )*8 + n] : 0.f;
    float hi = (n<8) ? src[pi_h(s0+1)*8 + n] : 0.f;
    wsU[W2F0 + i] = pk2(lo, hi);
    return;
  }
  i -= 8192;
  if (i < 15360){  // W1F1: B[k=q*8+j][n=t*16+c16], k>=8 -> 0
    int j2 = i & 3, l = (i>>2)&63, tt = (i>>8)&3, u = i>>10;
    int k0 = (l>>4)*8 + 2*j2;
    int n = tt*16 + (l&15);
    const float* src = (u<9) ? S.p[18] + (u*8)*64
                     : (u<12) ? S.p[22] + ((u-9)*8)*64
                              : S.p[26] + ((u-12)*8)*64;
    float lo = (k0   < 8) ? src[(k0  )*64 + n] : 0.f;
    float hi = (k0+1 < 8) ? src[(k0+1)*64 + n] : 0.f;
    wsU[W1F1 + i] = pk2(lo, hi);
    return;
  }
  i -= 15360;
  if (i < 7680){   // W2F1: pi-permuted k, n>=8 -> 0
    int j2 = i & 3, l = (i>>2)&63, ks = (i>>8)&1, u = i>>9;
    int s0 = ks*32 + (l>>4)*8 + 2*j2;
    int n = l & 15;
    const float* src = (u<9) ? S.p[20] + u*512
                     : (u<12) ? S.p[24] + (u-9)*512
                              : S.p[28] + (u-12)*512;
    float lo = (n<8) ? src[pi_h(s0  )*8 + n] : 0.f;
    float hi = (n<8) ? src[pi_h(s0+1)*8 + n] : 0.f;
    wsU[W2F1 + i] = pk2(lo, hi);
    return;
  }
  i -= 7680;
  if (i < 1024){   // b1P0
    int u = i>>6;
    const float* src = (u<9) ? S.p[1]+u*64 : (u<12) ? S.p[5]+(u-9)*64
                     : (u<15) ? S.p[9]+(u-12)*64 : S.p[14];
    wsF[OFF_b1P0 + i] = src[i&63];
    return;
  }
  i -= 1024;
  if (i < 256){    // b2P0 padded
    int u = i>>4, n = i&15;
    const float* src = (u<9) ? S.p[3]+u*8 : (u<12) ? S.p[7]+(u-9)*8
                     : (u<15) ? S.p[11]+(u-12)*8 : S.p[16];
    wsF[OFF_b2P0 + i] = (n<8) ? src[n] : 0.f;
    return;
  }
  i -= 256;
  if (i < 960){    // b1P1
    int u = i>>6;
    const float* src = (u<9) ? S.p[19]+u*64 : (u<12) ? S.p[23]+(u-9)*64
                               : S.p[27]+(u-12)*64;
    wsF[OFF_b1P1 + i] = src[i&63];
    return;
  }
  i -= 960;
  if (i < 240){    // b2P1 padded
    int u = i>>4, n = i&15;
    const float* src = (u<9) ? S.p[21]+u*8 : (u<12) ? S.p[25]+(u-9)*8
                               : S.p[29]+(u-12)*8;
    wsF[OFF_b2P1 + i] = (n<8) ? src[n] : 0.f;
    return;
  }
  i -= 240;
  if (i < 144){ wsF[OFF_G0W3 + i] = S.p[12][i]; return; }
  i -= 144;
  if (i < 96){ wsF[OFF_SG0W3 + i] = S.p[17][i]; return; }
  i -= 96;
  if (i < 144){ wsF[OFF_G1W3 + i] = S.p[30][i]; return; }
  i -= 144;
  if (i < 24){ wsF[OFF_TW + i] = S.p[31][i]; return; }
  i -= 24;
  wsF[OFF_Tb + i] = S.p[32][i];
}

template<int N>
__device__ __forceinline__ void softmaxT(float (&v)[N]){
  float m = v[0];
  #pragma unroll
  for (int i=1;i<N;i++) m = fmaxf(m, v[i]);
  float s = 0.f;
  #pragma unroll
  for (int i=0;i<N;i++){ v[i] = __expf(v[i]-m); s += v[i]; }
  float inv = 1.f/s;
  #pragma unroll
  for (int i=0;i<N;i++) v[i] *= inv;
}

__global__ __launch_bounds__(NT, 4) void ple_kernel(
    const float* __restrict__ emb, const int* __restrict__ cat,
    const u32* __restrict__ wsU, const float* __restrict__ P,
    float* __restrict__ out, int Btot)
{
  // LDS (u32): xsA [64e][48] bf16-pairs (x, k-pad 96); aliased after phase 1
  // as l1in [64e][36] (words 0..15 data, 16..31 zeros). ob [64r][65].
  // hbW per-wave H scratch [16e][36] (byte pitch 144: 16B-aligned rows).
  __shared__ u32 S_[9536];
  u32* xsA = S_;
  u32* ob  = S_ + 3072;
  u32* hbW = S_ + 7232;
  const int tid = threadIdx.x;
  const int e = tid & 63;
  const int su = __builtin_amdgcn_readfirstlane(tid >> 6);
  const int lane = tid & 63;
  const int q = lane >> 4;
  const int c16 = lane & 15;

  // ---- phase 0: gather x -> xsA bf16 [e][96], zero pad k 72..95 ----
  {
    const int eg = blockIdx.x*EPB + e;
    auto ldf = [&](int f){
      int idx = cat[eg*9 + f];
      const float* ep = emb + (long)idx*8;
      float4 a = *(const float4*)ep;
      float4 b = *(const float4*)(ep+4);
      u32* row = xsA + e*48 + f*4;
      row[0] = pk2(a.x, a.y); row[1] = pk2(a.z, a.w);
      row[2] = pk2(b.x, b.y); row[3] = pk2(b.z, b.w);
    };
    ldf(su); ldf(su+4);
    if (su == 0) ldf(8);
    u32* zr = xsA + e*48 + 36 + su*3;
    zr[0] = 0; zr[1] = 0; zr[2] = 0;
  }
  __syncthreads();

  // ---- phase 1: level-0 MFMA, wave su owns units 4su..4su+3 ----
  {
    u32* hbU = hbW + su*576;   // [16][36] u32
    #pragma unroll 1
    for (int k4 = 0; k4 < 4; k4++){
      const int u = su*4 + k4;
      short8 bf[3][4];
      #pragma unroll
      for (int s=0;s<3;s++)
        #pragma unroll
        for (int t=0;t<4;t++)
          bf[s][t] = *(const short8*)(wsU + W1F0 + (((u*3+s)*4+t)*64 + lane)*4);
      float bias[4];
      #pragma unroll
      for (int t=0;t<4;t++) bias[t] = P[OFF_b1P0 + u*64 + t*16 + c16];
      const float ob2 = P[OFF_b2P0 + u*16 + c16];
      short8 w2f[2];
      #pragma unroll
      for (int ks=0;ks<2;ks++)
        w2f[ks] = *(const short8*)(wsU + W2F0 + ((u*2+ks)*64 + lane)*4);

      #pragma unroll 1
      for (int m=0;m<4;m++){
        short8 af[3];
        #pragma unroll
        for (int s=0;s<3;s++)
          af[s] = *(const short8*)(xsA + (m*16 + c16)*48 + s*16 + q*4);
        floatx4 acc[4];
        #pragma unroll
        for (int t=0;t<4;t++) acc[t] = (floatx4){bias[t],bias[t],bias[t],bias[t]};
        #pragma unroll
        for (int s=0;s<3;s++)
          #pragma unroll
          for (int t=0;t<4;t++)
            acc[t] = __builtin_amdgcn_mfma_f32_16x16x32_bf16(af[s], bf[s][t], acc[t], 0,0,0);
        // H relu -> pi-packed bf16 pairs: word c16 = (t0,t1), 16+c16 = (t2,t3)
        #pragma unroll
        for (int r=0;r<4;r++){
          hbU[(q*4+r)*36 + c16]      = pk2(fmaxf(acc[0][r],0.f), fmaxf(acc[1][r],0.f));
          hbU[(q*4+r)*36 + 16 + c16] = pk2(fmaxf(acc[2][r],0.f), fmaxf(acc[3][r],0.f));
        }
        floatx4 oc = (floatx4){ob2, ob2, ob2, ob2};
        #pragma unroll
        for (int ks=0;ks<2;ks++){
          short8 haf = *(const short8*)(hbU + c16*36 + ks*16 + q*4);
          oc = __builtin_amdgcn_mfma_f32_16x16x32_bf16(haf, w2f[ks], oc, 0,0,0);
        }
        if (c16 < 8){
          u16* obp = (u16*)ob;
          #pragma unroll
          for (int r=0;r<4;r++)
            obp[(u*4 + (c16>>1))*130 + (m*16 + q*4 + r)*2 + (c16&1)] =
                (u16)f2bf(fmaxf(oc[r], 0.f));
        }
      }
    }
  }
  __syncthreads();

  // ---- phase 2: level-0 gates + mixing -> l1in (A-frag layout) ----
  u32* l1in = xsA;   // [64e][36]: 0..3 t0, 4..7 t1, 8..11 t2, 12..15 shared, 16..31 zero
  #pragma unroll
  for (int j=0;j<4;j++) l1in[e*36 + 16 + su*4 + j] = 0;
  if (su < 3){
    const int t = su;
    float g8[8];
    #pragma unroll
    for (int jw=0;jw<4;jw++){
      u32 w = ob[((12+t)*4+jw)*65 + e];
      g8[2*jw] = bflo(w); g8[2*jw+1] = bfhi(w);
    }
    float lg[6];
    #pragma unroll
    for (int m=0;m<6;m++){
      float s = 0.f;
      #pragma unroll
      for (int j=0;j<8;j++) s = fmaf(g8[j], P[OFF_G0W3 + t*48 + j*6 + m], s);
      lg[m] = s;
    }
    softmaxT<6>(lg);
    float in8[8] = {0,0,0,0,0,0,0,0};
    #pragma unroll
    for (int x=0;x<6;x++){
      const int uu = (x<3) ? t*3+x : 9+(x-3);
      float wv = lg[x];
      #pragma unroll
      for (int jw=0;jw<4;jw++){
        u32 w = ob[(uu*4+jw)*65 + e];
        in8[2*jw]   = fmaf(wv, bflo(w), in8[2*jw]);
        in8[2*jw+1] = fmaf(wv, bfhi(w), in8[2*jw+1]);
      }
    }
    #pragma unroll
    for (int jw=0;jw<4;jw++)
      l1in[e*36 + t*4 + jw] = pk2(in8[2*jw], in8[2*jw+1]);
  } else {
    float g8[8];
    #pragma unroll
    for (int jw=0;jw<4;jw++){
      u32 w = ob[(15*4+jw)*65 + e];
      g8[2*jw] = bflo(w); g8[2*jw+1] = bfhi(w);
    }
    float lw[12];
    #pragma unroll
    for (int m=0;m<12;m++){
      float s = 0.f;
      #pragma unroll
      for (int j=0;j<8;j++) s = fmaf(g8[j], P[OFF_SG0W3 + j*12 + m], s);
      lw[m] = s;
    }
    softmaxT<12>(lw);
    float in8[8] = {0,0,0,0,0,0,0,0};
    #pragma unroll
    for (int uu=0;uu<12;uu++){
      float wv = lw[uu];
      #pragma unroll
      for (int jw=0;jw<4;jw++){
        u32 w = ob[(uu*4+jw)*65 + e];
        in8[2*jw]   = fmaf(wv, bflo(w), in8[2*jw]);
        in8[2*jw+1] = fmaf(wv, bfhi(w), in8[2*jw+1]);
      }
    }
    #pragma unroll
    for (int jw=0;jw<4;jw++)
      l1in[e*36 + 12 + jw] = pk2(in8[2*jw], in8[2*jw+1]);
  }
  __syncthreads();

  // ---- phase 3: level-1 MFMA (15 units, K=8 zero-padded to 32) ----
  {
    u32* hbU = hbW + su*576;
    #pragma unroll 1
    for (int k4=0;k4<4;k4++){
      const int u = su*4 + k4;
      if (u >= 15) break;
      const int base_u = (u<9) ? (u/3)*4 : ((u<12) ? 12 : (u-12)*4);
      const int aoff = (q==0) ? base_u : (16 + q*4);   // q>=1 -> zero region
      short8 bf1[4];
      #pragma unroll
      for (int t=0;t<4;t++)
        bf1[t] = *(const short8*)(wsU + W1F1 + ((u*4+t)*64 + lane)*4);
      float bias[4];
      #pragma unroll
      for (int t=0;t<4;t++) bias[t] = P[OFF_b1P1 + u*64 + t*16 + c16];
      const float ob2 = P[OFF_b2P1 + u*16 + c16];
      short8 w2f[2];
      #pragma unroll
      for (int ks=0;ks<2;ks++)
        w2f[ks] = *(const short8*)(wsU + W2F1 + ((u*2+ks)*64 + lane)*4);

      #pragma unroll 1
      for (int m=0;m<4;m++){
        short8 af = *(const short8*)(l1in + (m*16 + c16)*36 + aoff);
        floatx4 acc[4];
        #pragma unroll
        for (int t=0;t<4;t++) acc[t] = (floatx4){bias[t],bias[t],bias[t],bias[t]};
        #pragma unroll
        for (int t=0;t<4;t++)
          acc[t] = __builtin_amdgcn_mfma_f32_16x16x32_bf16(af, bf1[t], acc[t], 0,0,0);
        #pragma unroll
        for (int r=0;r<4;r++){
          hbU[(q*4+r)*36 + c16]      = pk2(fmaxf(acc[0][r],0.f), fmaxf(acc[1][r],0.f));
          hbU[(q*4+r)*36 + 16 + c16] = pk2(fmaxf(acc[2][r],0.f), fmaxf(acc[3][r],0.f));
        }
        floatx4 oc = (floatx4){ob2, ob2, ob2, ob2};
        #pragma unroll
        for (int ks=0;ks<2;ks++){
          short8 haf = *(const short8*)(hbU + c16*36 + ks*16 + q*4);
          oc = __builtin_amdgcn_mfma_f32_16x16x32_bf16(haf, w2f[ks], oc, 0,0,0);
        }
        if (c16 < 8){
          u16* obp = (u16*)ob;
          #pragma unroll
          for (int r=0;r<4;r++)
            obp[(u*4 + (c16>>1))*130 + (m*16 + q*4 + r)*2 + (c16&1)] =
                (u16)f2bf(fmaxf(oc[r], 0.f));
        }
      }
    }
  }
  __syncthreads();

  // ---- phase 4: level-1 gates + mixing + towers ----
  if (su < 3){
    const int t = su;
    float g8[8];
    #pragma unroll
    for (int jw=0;jw<4;jw++){
      u32 w = ob[((12+t)*4+jw)*65 + e];
      g8[2*jw] = bflo(w); g8[2*jw+1] = bfhi(w);
    }
    float lg[6];
    #pragma unroll
    for (int m=0;m<6;m++){
      float s = 0.f;
      #pragma unroll
      for (int j=0;j<8;j++) s = fmaf(g8[j], P[OFF_G1W3 + t*48 + j*6 + m], s);
      lg[m] = s;
    }
    softmaxT<6>(lg);
    float t1[8] = {0,0,0,0,0,0,0,0};
    #pragma unroll
    for (int x=0;x<6;x++){
      const int uu = (x<3) ? t*3+x : 9+(x-3);
      float wv = lg[x];
      #pragma unroll
      for (int jw=0;jw<4;jw++){
        u32 w = ob[(uu*4+jw)*65 + e];
        t1[2*jw]   = fmaf(wv, bflo(w), t1[2*jw]);
        t1[2*jw+1] = fmaf(wv, bfhi(w), t1[2*jw+1]);
      }
    }
    float s = P[OFF_Tb + t];
    #pragma unroll
    for (int j=0;j<8;j++) s = fmaf(t1[j], P[OFF_TW + t*8 + j], s);
    out[t*Btot + blockIdx.x*EPB + e] = 1.f/(1.f + __expf(-s));
  }
}

extern "C" void kernel_launch(void* const* d_in, const int* in_sizes, int n_in,
                              void* d_out, int out_size, void* d_ws, size_t ws_size,
                              hipStream_t stream)
{
  const float* emb = (const float*)d_in[0];
  const int* cat = (const int*)d_in[34];
  float* out = (float*)d_out;
  u32* wsU = (u32*)d_ws;
  float* wsF = (float*)d_ws;
  PSrc S;
  for (int k=0;k<33;k++) S.p[k] = (const float*)d_in[k+1];
  const int B = in_sizes[34] / 9;   // 131072

  cvt_kernel<<<(CVT_TOTAL+255)/256, 256, 0, stream>>>(S, wsU, wsF);
  ple_kernel<<<B/EPB, NT, 0, stream>>>(emb, cat, wsU, wsF, out, B);
}